// Round 9
// baseline (138.750 us; speedup 1.0000x reference)
//
#include <hip/hip_runtime.h>

#define BB 2
#define SS 2048
#define EE 768
#define HH 12
#define DKK 64

typedef _Float16 h16;
typedef _Float16 half8 __attribute__((ext_vector_type(8)));
typedef _Float16 h16x4 __attribute__((ext_vector_type(4)));
typedef float f32x4 __attribute__((ext_vector_type(4)));

// ---------------- mask packing: int32 [S,S] -> 1 bit, word = 32 cols ----------------
__global__ void pack_mask_k(const int* __restrict__ mask, unsigned* __restrict__ mp) {
    int idx = blockIdx.x * 256 + threadIdx.x;      // 0 .. S*S/32-1
    int base = idx * 32;
    const int4* m4 = (const int4*)(mask + base);
    unsigned w = 0;
#pragma unroll
    for (int i = 0; i < 8; ++i) {
        int4 v = m4[i];
        if (v.x) w |= 1u << (i * 4 + 0);
        if (v.y) w |= 1u << (i * 4 + 1);
        if (v.z) w |= 1u << (i * 4 + 2);
        if (v.w) w |= 1u << (i * 4 + 3);
    }
    mp[idx] = w;
}

// ---------------- projection GEMM: 64m x 128n tiles, 1152 blocks (occupancy-first) ----------------
// k/q row-major [b,h,s,d]; v TRANSPOSED [b,h,d,s].
__launch_bounds__(256)
__global__ void proj_gemm_k(const float* __restrict__ srcK, const float* __restrict__ srcQ,
                            const float* __restrict__ srcV, const float* __restrict__ Wk,
                            const float* __restrict__ bk,
                            h16* __restrict__ kh, h16* __restrict__ qh, h16* __restrict__ vtp) {
    __shared__ h16 As[64 * 64];                     // [64 rows][8 granules of 16B], swizzled
    __shared__ h16 Bs[128 * 64];
    const int bid = blockIdx.x;                     // 0..1151
    const int idx = (bid & 7) * 144 + (bid >> 3);   // XCD-contiguous logical index
    const int z = idx / 384;
    const int rem = idx % 384;
    const int m0 = (rem / 6) * 64, n0 = (rem % 6) * 128;
    const float* src = (z == 0) ? srcK : ((z == 1) ? srcQ : srcV);
    const int tid = threadIdx.x, lane = tid & 63, wid = tid >> 6;
    const int l = lane & 15, gq = lane >> 4;
    f32x4 acc[4][2] = {};                           // wave: 64m x 32n

    for (int k0 = 0; k0 < EE; k0 += 64) {
#pragma unroll
        for (int it = 0; it < 2; ++it) {            // A: 64x64 fp32 -> fp16
            int e8 = it * 256 + tid;
            int row = e8 >> 3, g = e8 & 7;
            const float* pa = src + (m0 + row) * EE + k0 + g * 8;
            float4 a0 = *(const float4*)pa, a1 = *(const float4*)(pa + 4);
            half8 ha = {(h16)a0.x, (h16)a0.y, (h16)a0.z, (h16)a0.w,
                        (h16)a1.x, (h16)a1.y, (h16)a1.z, (h16)a1.w};
            *(half8*)((char*)As + row * 128 + ((g ^ (row & 7)) << 4)) = ha;
        }
#pragma unroll
        for (int it = 0; it < 4; ++it) {            // B: 128x64 fp32 -> fp16
            int e8 = it * 256 + tid;
            int row = e8 >> 3, g = e8 & 7;
            const float* pb = Wk + (n0 + row) * EE + k0 + g * 8;
            float4 b0 = *(const float4*)pb, b1 = *(const float4*)(pb + 4);
            half8 hb = {(h16)b0.x, (h16)b0.y, (h16)b0.z, (h16)b0.w,
                        (h16)b1.x, (h16)b1.y, (h16)b1.z, (h16)b1.w};
            *(half8*)((char*)Bs + row * 128 + ((g ^ (row & 7)) << 4)) = hb;
        }
        __syncthreads();
#pragma unroll
        for (int ks = 0; ks < 2; ++ks) {
            half8 a[4], b[2];
#pragma unroll
            for (int rf = 0; rf < 4; ++rf) {
                int row = rf * 16 + l;
                int g = (ks * 4 + gq) ^ (row & 7);
                a[rf] = *(const half8*)((const char*)As + row * 128 + (g << 4));
            }
#pragma unroll
            for (int cf = 0; cf < 2; ++cf) {
                int row = wid * 32 + cf * 16 + l;
                int g = (ks * 4 + gq) ^ (row & 7);
                b[cf] = *(const half8*)((const char*)Bs + row * 128 + (g << 4));
            }
            __builtin_amdgcn_s_setprio(1);
#pragma unroll
            for (int rf = 0; rf < 4; ++rf)
#pragma unroll
                for (int cf = 0; cf < 2; ++cf)
                    acc[rf][cf] = __builtin_amdgcn_mfma_f32_16x16x32_f16(a[rf], b[cf], acc[rf][cf], 0, 0, 0);
            __builtin_amdgcn_s_setprio(0);
        }
        __syncthreads();
    }
    if (z == 2) {
        // V: write transposed vt[(b*H+h)*64 + d][s], 4 consecutive s packed
#pragma unroll
        for (int rf = 0; rf < 4; ++rf)
#pragma unroll
            for (int cf = 0; cf < 2; ++cf) {
                int n = n0 + wid * 32 + cf * 16 + l;
                float bias = bk[n];
                int h = n >> 6, d = n & 63;
                int mb = m0 + rf * 16 + gq * 4;
                int b = mb >> 11, s = mb & 2047;
                h16x4 pv = {(h16)(acc[rf][cf][0] + bias), (h16)(acc[rf][cf][1] + bias),
                            (h16)(acc[rf][cf][2] + bias), (h16)(acc[rf][cf][3] + bias)};
                *(h16x4*)(vtp + ((long)((b * HH + h) * 64 + d)) * SS + s) = pv;
            }
    } else {
        h16* dst = (z == 0) ? kh : qh;
#pragma unroll
        for (int rf = 0; rf < 4; ++rf)
#pragma unroll
            for (int cf = 0; cf < 2; ++cf) {
                int n = n0 + wid * 32 + cf * 16 + l;
                float bias = bk[n];
                int h = n >> 6, d = n & 63;
#pragma unroll
                for (int j = 0; j < 4; ++j) {
                    int m = m0 + rf * 16 + gq * 4 + j;
                    int b = m >> 11, s = m & 2047;
                    dst[(((long)(b * HH + h) * SS + s) << 6) + d] = (h16)(acc[rf][cf][j] + bias);
                }
            }
    }
}

// ---------------- flash attention: 4 waves x 16 q-rows, LDS-staged K/V^T tiles ----------------
struct StageRegs { half8 k[2], v[2]; };

__device__ __forceinline__ void ld_stage(StageRegs& r, const h16* __restrict__ kg,
                                         const h16* __restrict__ vg,
                                         int kv0, int wid, int lane) {
    int rr = lane >> 3;
    int sg = (lane & 7) ^ rr;                  // pre-swizzled global granule
#pragma unroll
    for (int i = 0; i < 2; ++i) {
        int row = wid * 16 + i * 8 + rr;       // row & 7 == rr
        r.k[i] = *(const half8*)(kg + (long)(kv0 + row) * DKK + sg * 8);
        r.v[i] = *(const half8*)(vg + (long)row * SS + kv0 + sg * 8);
    }
}

__device__ __forceinline__ void st_stage(h16* __restrict__ kl, h16* __restrict__ vl,
                                         const StageRegs& r, int wid, int lane) {
#pragma unroll
    for (int i = 0; i < 2; ++i) {              // linear store: lane*16B within wave chunk
        *(half8*)(kl + wid * 1024 + i * 512 + lane * 8) = r.k[i];
        *(half8*)(vl + wid * 1024 + i * 512 + lane * 8) = r.v[i];
    }
}

__launch_bounds__(256, 3)
__global__ void attn_k(const h16* __restrict__ qh, const h16* __restrict__ kh,
                       const h16* __restrict__ vt, const unsigned long long* __restrict__ mp,
                       h16* __restrict__ xh) {
    __shared__ h16 Kbuf[2][4096];
    __shared__ h16 Vbuf[2][4096];
    __shared__ char Ps[8192];                  // per-wave private 2KB P tile
    const int tid = threadIdx.x;
    const int lane = tid & 63, wid = tid >> 6;
    const int l = lane & 15, g = lane >> 4;
    const int bid = blockIdx.x;
    const int idx = (bid & 7) * 96 + (bid >> 3);
    const int q0 = (idx & 31) * 64 + wid * 16;
    const int bh = idx >> 5;
    const long base = (long)bh * SS * DKK;
    const h16* kg = kh + base;
    const h16* vg = vt + base;
    char* pbase = Ps + wid * 2048;

    half8 qf0, qf1;
    {
        const h16* qp = qh + base + (long)(q0 + l) * DKK + g * 8;
        qf0 = *(const half8*)qp;
        qf1 = *(const half8*)(qp + 32);
    }
    const unsigned long long* mrow = mp + (long)(q0 + l) * (SS / 64);

    f32x4 o[4] = {};
    float m2 = -INFINITY, lsum = 0.f;
    const float K2 = 8.0f * 1.44269504f;       // sqrt(dk) * log2(e)  (source multiplies!)
    const float C2 = 1e-6f * 1.44269504f;      // masked value in log2 domain

    StageRegs sr;
    ld_stage(sr, kg, vg, 0, wid, lane);        // tile 0
    st_stage(Kbuf[0], Vbuf[0], sr, wid, lane);
    __syncthreads();

    for (int t = 0; t < 32; ++t) {
        const h16* Kl = Kbuf[t & 1];
        const h16* Vl = Vbuf[t & 1];
        ld_stage(sr, kg, vg, ((t + 1) & 31) * 64, wid, lane);
        half8 ka[4], kb[4];
#pragma unroll
        for (int cf = 0; cf < 4; ++cf) {
            int row = cf * 16 + l;
            const h16* kp = Kl + row * 64;
            ka[cf] = *(const half8*)(kp + ((g ^ (row & 7)) << 3));
            kb[cf] = *(const half8*)(kp + (((4 + g) ^ (row & 7)) << 3));
        }
        f32x4 s[4];
        __builtin_amdgcn_s_setprio(1);
#pragma unroll
        for (int cf = 0; cf < 4; ++cf) {
            f32x4 z = {};
            z = __builtin_amdgcn_mfma_f32_16x16x32_f16(ka[cf], qf0, z, 0, 0, 0);
            z = __builtin_amdgcn_mfma_f32_16x16x32_f16(kb[cf], qf1, z, 0, 0, 0);
            s[cf] = z;
        }
        __builtin_amdgcn_s_setprio(0);
        unsigned long long mw = mrow[t];
        unsigned w0 = (unsigned)mw, w1 = (unsigned)(mw >> 32);
#pragma unroll
        for (int cf = 0; cf < 4; ++cf) {
            unsigned wcb = (cf & 2) ? w1 : w0;
#pragma unroll
            for (int j = 0; j < 4; ++j) {
                unsigned sh = ((cf & 1) << 4) + g * 4 + j;
                s[cf][j] = ((wcb >> sh) & 1u) ? s[cf][j] * K2 : C2;
            }
        }
        float pmax = fmaxf(fmaxf(s[0][0], s[0][1]), fmaxf(s[0][2], s[0][3]));
#pragma unroll
        for (int cf = 1; cf < 4; ++cf)
            pmax = fmaxf(pmax, fmaxf(fmaxf(s[cf][0], s[cf][1]), fmaxf(s[cf][2], s[cf][3])));
        if (!__all(pmax <= m2 + 11.0f)) {      // defer-max (T13)
            pmax = fmaxf(pmax, __shfl_xor(pmax, 16));
            pmax = fmaxf(pmax, __shfl_xor(pmax, 32));
            float mnew = fmaxf(m2, pmax);
            float alpha = __builtin_amdgcn_exp2f(m2 - mnew);
#pragma unroll
            for (int df = 0; df < 4; ++df)
#pragma unroll
                for (int j = 0; j < 4; ++j) o[df][j] *= alpha;
            lsum *= alpha;
            m2 = mnew;
        }
        float rs = 0.f;
#pragma unroll
        for (int cf = 0; cf < 4; ++cf)
#pragma unroll
            for (int j = 0; j < 4; ++j) {
                float p = __builtin_amdgcn_exp2f(s[cf][j] - m2);
                s[cf][j] = p;
                rs += p;
            }
        lsum += rs;
#pragma unroll
        for (int cf = 0; cf < 4; ++cf) {
            h16x4 pk = {(h16)s[cf][0], (h16)s[cf][1], (h16)s[cf][2], (h16)s[cf][3]};
            int gran = (2 * cf + (g >> 1)) ^ (l & 7);
            *(h16x4*)(pbase + l * 128 + gran * 16 + (g & 1) * 8) = pk;
        }
#pragma unroll
        for (int ks = 0; ks < 2; ++ks) {
            int gr = (ks * 4 + g) ^ (l & 7);
            half8 pf = *(const half8*)(pbase + l * 128 + gr * 16);
            half8 vk[4];
#pragma unroll
            for (int df = 0; df < 4; ++df) {
                int row = df * 16 + l;
                vk[df] = *(const half8*)(Vl + row * 64 + (((ks * 4 + g) ^ (row & 7)) << 3));
            }
            __builtin_amdgcn_s_setprio(1);
#pragma unroll
            for (int df = 0; df < 4; ++df)
                o[df] = __builtin_amdgcn_mfma_f32_16x16x32_f16(vk[df], pf, o[df], 0, 0, 0);
            __builtin_amdgcn_s_setprio(0);
        }
        st_stage(Kbuf[(t + 1) & 1], Vbuf[(t + 1) & 1], sr, wid, lane);
        __syncthreads();
    }

    lsum += __shfl_xor(lsum, 16);
    lsum += __shfl_xor(lsum, 32);
    float inv = 1.0f / lsum;
    int b = bh / HH, h = bh % HH;
    h16* xp = xh + (long)(b * SS + q0 + l) * EE + h * 64 + g * 4;
#pragma unroll
    for (int df = 0; df < 4; ++df) {
        h16x4 v4 = {(h16)(o[df][0] * inv), (h16)(o[df][1] * inv),
                    (h16)(o[df][2] * inv), (h16)(o[df][3] * inv)};
        *(h16x4*)(xp + df * 16) = v4;
    }
}

// ---------------- output GEMM: 64m x 64n tiles, 768 blocks ----------------
__launch_bounds__(256)
__global__ void out_gemm_k(const h16* __restrict__ xh, const float* __restrict__ Wo,
                           const float* __restrict__ bo, float* __restrict__ out) {
    __shared__ h16 As[64 * 64];
    __shared__ h16 Bs[64 * 64];
    const int bid = blockIdx.x;                    // 0..767
    const int idx = (bid & 7) * 96 + (bid >> 3);
    const int m0 = (idx / 12) * 64, n0 = (idx % 12) * 64;
    const int tid = threadIdx.x, lane = tid & 63, wid = tid >> 6;
    const int l = lane & 15, gq = lane >> 4;
    const int wr = wid >> 1, wc = wid & 1;
    f32x4 acc[2][2] = {};                          // wave: 32m x 32n

    for (int k0 = 0; k0 < EE; k0 += 64) {
#pragma unroll
        for (int it = 0; it < 2; ++it) {
            int e8 = it * 256 + tid;
            int row = e8 >> 3, g = e8 & 7;
            half8 ha = *(const half8*)(xh + (m0 + row) * EE + k0 + g * 8);
            const float* pb = Wo + (n0 + row) * EE + k0 + g * 8;
            float4 b0 = *(const float4*)pb, b1 = *(const float4*)(pb + 4);
            half8 hb = {(h16)b0.x, (h16)b0.y, (h16)b0.z, (h16)b0.w,
                        (h16)b1.x, (h16)b1.y, (h16)b1.z, (h16)b1.w};
            int sw = (g ^ (row & 7)) << 4;
            *(half8*)((char*)As + row * 128 + sw) = ha;
            *(half8*)((char*)Bs + row * 128 + sw) = hb;
        }
        __syncthreads();
#pragma unroll
        for (int ks = 0; ks < 2; ++ks) {
            half8 a[2], b[2];
#pragma unroll
            for (int rf = 0; rf < 2; ++rf) {
                int row = wr * 32 + rf * 16 + l;
                int g = (ks * 4 + gq) ^ (row & 7);
                a[rf] = *(const half8*)((const char*)As + row * 128 + (g << 4));
            }
#pragma unroll
            for (int cf = 0; cf < 2; ++cf) {
                int row = wc * 32 + cf * 16 + l;
                int g = (ks * 4 + gq) ^ (row & 7);
                b[cf] = *(const half8*)((const char*)Bs + row * 128 + (g << 4));
            }
            __builtin_amdgcn_s_setprio(1);
#pragma unroll
            for (int rf = 0; rf < 2; ++rf)
#pragma unroll
                for (int cf = 0; cf < 2; ++cf)
                    acc[rf][cf] = __builtin_amdgcn_mfma_f32_16x16x32_f16(a[rf], b[cf], acc[rf][cf], 0, 0, 0);
            __builtin_amdgcn_s_setprio(0);
        }
        __syncthreads();
    }
#pragma unroll
    for (int rf = 0; rf < 2; ++rf)
#pragma unroll
        for (int cf = 0; cf < 2; ++cf) {
            int n = n0 + wc * 32 + cf * 16 + l;
            float bias = bo[n];
#pragma unroll
            for (int j = 0; j < 4; ++j) {
                int m = m0 + wr * 32 + rf * 16 + gq * 4 + j;
                out[(long)m * EE + n] = acc[rf][cf][j] + bias;
            }
        }
}

extern "C" void kernel_launch(void* const* d_in, const int* in_sizes, int n_in,
                              void* d_out, int out_size, void* d_ws, size_t ws_size,
                              hipStream_t stream) {
    const float* key   = (const float*)d_in[0];
    const float* query = (const float*)d_in[1];
    const float* value = (const float*)d_in[2];
    const int*   mask  = (const int*)d_in[3];
    const float* Wk    = (const float*)d_in[4];
    const float* bk    = (const float*)d_in[5];
    const float* Wo    = (const float*)d_in[6];
    const float* bo    = (const float*)d_in[7];

    char* ws = (char*)d_ws;
    h16* qh = (h16*)(ws + 0);
    h16* kh = (h16*)(ws + 6291456);
    h16* vt = (h16*)(ws + 12582912);
    h16* xh = (h16*)(ws + 18874368);
    unsigned* mp = (unsigned*)(ws + 25165824);
    float* out = (float*)d_out;

    hipLaunchKernelGGL(pack_mask_k, dim3(SS * SS / 32 / 256), dim3(256), 0, stream, mask, mp);
    hipLaunchKernelGGL(proj_gemm_k, dim3(1152), dim3(256), 0, stream,
                       key, query, value, Wk, bk, kh, qh, vt);
    hipLaunchKernelGGL(attn_k, dim3(SS / 64 * BB * HH), dim3(256), 0, stream,
                       qh, kh, vt, (const unsigned long long*)mp, xh);
    hipLaunchKernelGGL(out_gemm_k, dim3(768), dim3(256), 0, stream, xh, Wo, bo, out);
}

// Round 10
// 117.087 us; speedup vs baseline: 1.1850x; 1.1850x over previous
//
#include <hip/hip_runtime.h>

#define BB 2
#define SS 2048
#define EE 768
#define HH 12
#define DKK 64

typedef _Float16 h16;
typedef _Float16 half8 __attribute__((ext_vector_type(8)));
typedef _Float16 h16x4 __attribute__((ext_vector_type(4)));
typedef float f32x4 __attribute__((ext_vector_type(4)));

// direct global->LDS 16B async copy (linear LDS dest = wave base + lane*16)
__device__ __forceinline__ void gl_lds16(const void* g, void* l) {
    __builtin_amdgcn_global_load_lds(
        (const __attribute__((address_space(1))) unsigned int*)g,
        (__attribute__((address_space(3))) unsigned int*)l, 16, 0, 0);
}

// ---------------- mask packing: int32 [S,S] -> 1 bit, word = 32 cols ----------------
__global__ void pack_mask_k(const int* __restrict__ mask, unsigned* __restrict__ mp) {
    int idx = blockIdx.x * 256 + threadIdx.x;      // 0 .. S*S/32-1
    int base = idx * 32;
    const int4* m4 = (const int4*)(mask + base);
    unsigned w = 0;
#pragma unroll
    for (int i = 0; i < 8; ++i) {
        int4 v = m4[i];
        if (v.x) w |= 1u << (i * 4 + 0);
        if (v.y) w |= 1u << (i * 4 + 1);
        if (v.z) w |= 1u << (i * 4 + 2);
        if (v.w) w |= 1u << (i * 4 + 3);
    }
    mp[idx] = w;
}

// ---------------- fp32 -> fp16 pre-convert (key,query,value,Wk,Wo) ----------------
// 1327104 granules of 8 elems; 5184 blocks x 256.
__global__ void cvt_k(const float* __restrict__ sK, const float* __restrict__ sQ,
                      const float* __restrict__ sV, const float* __restrict__ sWk,
                      const float* __restrict__ sWo,
                      h16* __restrict__ dK, h16* __restrict__ dQ, h16* __restrict__ dV,
                      h16* __restrict__ dWk, h16* __restrict__ dWo) {
    long g = (long)blockIdx.x * 256 + threadIdx.x;
    const float* src;
    h16* dst;
    long off;
    if (g < 393216)        { src = sK;  dst = dK;  off = g; }
    else if (g < 786432)   { src = sQ;  dst = dQ;  off = g - 393216; }
    else if (g < 1179648)  { src = sV;  dst = dV;  off = g - 786432; }
    else if (g < 1253376)  { src = sWk; dst = dWk; off = g - 1179648; }
    else                   { src = sWo; dst = dWo; off = g - 1253376; }
    const float* p = src + off * 8;
    float4 a = *(const float4*)p, b = *(const float4*)(p + 4);
    half8 h = {(h16)a.x, (h16)a.y, (h16)a.z, (h16)a.w,
               (h16)b.x, (h16)b.y, (h16)b.z, (h16)b.w};
    *(half8*)(dst + off * 8) = h;
}

// ---------------- projection GEMM: fp16 in, global_load_lds staging ----------------
// 64m x 128n tiles, 1152 blocks XCD-swizzled. k/q out row-major [b,h,s,d]; v TRANSPOSED.
// LDS tile layout: [row][slot], slot s of row r holds global granule s^(r&7).
__launch_bounds__(256)
__global__ void proj_gemm_k(const h16* __restrict__ keyh, const h16* __restrict__ qryh,
                            const h16* __restrict__ valh, const h16* __restrict__ Wkh,
                            const float* __restrict__ bk,
                            h16* __restrict__ kh, h16* __restrict__ qh, h16* __restrict__ vtp) {
    __shared__ h16 As[64 * 64];                     // 8 KB
    __shared__ h16 Bs[128 * 64];                    // 16 KB
    const int bid = blockIdx.x;                     // 0..1151
    const int idx = (bid & 7) * 144 + (bid >> 3);
    const int z = idx / 384;
    const int rem = idx % 384;
    const int m0 = (rem / 6) * 64, n0 = (rem % 6) * 128;
    const h16* src = (z == 0) ? keyh : ((z == 1) ? qryh : valh);
    const int tid = threadIdx.x, lane = tid & 63, wid = tid >> 6;
    const int l = lane & 15, gq = lane >> 4;
    f32x4 acc[4][2] = {};                           // wave: 64m x 32n

    for (int k0 = 0; k0 < EE; k0 += 64) {
#pragma unroll
        for (int it = 0; it < 2; ++it) {            // A: 64 rows
            int e = it * 256 + tid;
            int row = e >> 3, slot = e & 7;
            gl_lds16(src + (long)(m0 + row) * EE + k0 + ((slot ^ (row & 7)) << 3), As + e * 8);
        }
#pragma unroll
        for (int it = 0; it < 4; ++it) {            // B: 128 rows
            int e = it * 256 + tid;
            int row = e >> 3, slot = e & 7;
            gl_lds16(Wkh + (long)(n0 + row) * EE + k0 + ((slot ^ (row & 7)) << 3), Bs + e * 8);
        }
        __syncthreads();                            // drains vmcnt
#pragma unroll
        for (int ks = 0; ks < 2; ++ks) {
            half8 a[4], b[2];
#pragma unroll
            for (int rf = 0; rf < 4; ++rf) {
                int row = rf * 16 + l;
                int g = (ks * 4 + gq) ^ (row & 7);
                a[rf] = *(const half8*)((const char*)As + row * 128 + (g << 4));
            }
#pragma unroll
            for (int cf = 0; cf < 2; ++cf) {
                int row = wid * 32 + cf * 16 + l;
                int g = (ks * 4 + gq) ^ (row & 7);
                b[cf] = *(const half8*)((const char*)Bs + row * 128 + (g << 4));
            }
            __builtin_amdgcn_s_setprio(1);
#pragma unroll
            for (int rf = 0; rf < 4; ++rf)
#pragma unroll
                for (int cf = 0; cf < 2; ++cf)
                    acc[rf][cf] = __builtin_amdgcn_mfma_f32_16x16x32_f16(a[rf], b[cf], acc[rf][cf], 0, 0, 0);
            __builtin_amdgcn_s_setprio(0);
        }
        __syncthreads();
    }
    if (z == 2) {
        // V: write transposed vt[(b*H+h)*64 + d][s], 4 consecutive s packed
#pragma unroll
        for (int rf = 0; rf < 4; ++rf)
#pragma unroll
            for (int cf = 0; cf < 2; ++cf) {
                int n = n0 + wid * 32 + cf * 16 + l;
                float bias = bk[n];
                int h = n >> 6, d = n & 63;
                int mb = m0 + rf * 16 + gq * 4;
                int b = mb >> 11, s = mb & 2047;
                h16x4 pv = {(h16)(acc[rf][cf][0] + bias), (h16)(acc[rf][cf][1] + bias),
                            (h16)(acc[rf][cf][2] + bias), (h16)(acc[rf][cf][3] + bias)};
                *(h16x4*)(vtp + ((long)((b * HH + h) * 64 + d)) * SS + s) = pv;
            }
    } else {
        h16* dst = (z == 0) ? kh : qh;
#pragma unroll
        for (int rf = 0; rf < 4; ++rf)
#pragma unroll
            for (int cf = 0; cf < 2; ++cf) {
                int n = n0 + wid * 32 + cf * 16 + l;
                float bias = bk[n];
                int h = n >> 6, d = n & 63;
#pragma unroll
                for (int j = 0; j < 4; ++j) {
                    int m = m0 + rf * 16 + gq * 4 + j;
                    int b = m >> 11, s = m & 2047;
                    dst[(((long)(b * HH + h) * SS + s) << 6) + d] = (h16)(acc[rf][cf][j] + bias);
                }
            }
    }
}

// ---------------- flash attention: 4 waves x 16 q-rows, global_load_lds K/V^T staging ----------------
__launch_bounds__(256, 3)
__global__ void attn_k(const h16* __restrict__ qh, const h16* __restrict__ kh,
                       const h16* __restrict__ vt, const unsigned long long* __restrict__ mp,
                       h16* __restrict__ xh) {
    __shared__ h16 Kbuf[2][4096];
    __shared__ h16 Vbuf[2][4096];
    __shared__ char Ps[8192];                  // per-wave private 2KB P tile
    const int tid = threadIdx.x;
    const int lane = tid & 63, wid = tid >> 6;
    const int l = lane & 15, g = lane >> 4;
    const int bid = blockIdx.x;
    const int idx = (bid & 7) * 96 + (bid >> 3);
    const int q0 = (idx & 31) * 64 + wid * 16;
    const int bh = idx >> 5;
    const long base = (long)bh * SS * DKK;
    const h16* kg = kh + base;
    const h16* vg = vt + base;
    char* pbase = Ps + wid * 2048;
    const int rr = lane >> 3, sg = (lane & 7) ^ (lane >> 3);   // pre-swizzled granule

    half8 qf0, qf1;
    {
        const h16* qp = qh + base + (long)(q0 + l) * DKK + g * 8;
        qf0 = *(const half8*)qp;
        qf1 = *(const half8*)(qp + 32);
    }
    const unsigned long long* mrow = mp + (long)(q0 + l) * (SS / 64);

    f32x4 o[4] = {};
    float m2 = -INFINITY, lsum = 0.f;
    const float K2 = 8.0f * 1.44269504f;       // sqrt(dk) * log2(e)  (source multiplies!)
    const float C2 = 1e-6f * 1.44269504f;      // masked value in log2 domain

    // prologue: stage tile 0 directly to LDS
#pragma unroll
    for (int i = 0; i < 2; ++i) {
        int row = wid * 16 + i * 8 + rr;
        gl_lds16(kg + (long)row * DKK + sg * 8, &Kbuf[0][wid * 1024 + i * 512 + lane * 8]);
        gl_lds16(vg + (long)row * SS + sg * 8, &Vbuf[0][wid * 1024 + i * 512 + lane * 8]);
    }
    __syncthreads();

    for (int t = 0; t < 32; ++t) {
        const h16* Kl = Kbuf[t & 1];
        const h16* Vl = Vbuf[t & 1];
        // ---- issue next tile's global->LDS copies (in flight across compute) ----
        {
            int kv0n = ((t + 1) & 31) * 64;
            int nb = (t + 1) & 1;
#pragma unroll
            for (int i = 0; i < 2; ++i) {
                int row = wid * 16 + i * 8 + rr;
                gl_lds16(kg + (long)(kv0n + row) * DKK + sg * 8, &Kbuf[nb][wid * 1024 + i * 512 + lane * 8]);
                gl_lds16(vg + (long)row * SS + kv0n + sg * 8, &Vbuf[nb][wid * 1024 + i * 512 + lane * 8]);
            }
        }
        half8 ka[4], kb[4];
#pragma unroll
        for (int cf = 0; cf < 4; ++cf) {
            int row = cf * 16 + l;
            const h16* kp = Kl + row * 64;
            ka[cf] = *(const half8*)(kp + ((g ^ (row & 7)) << 3));
            kb[cf] = *(const half8*)(kp + (((4 + g) ^ (row & 7)) << 3));
        }
        f32x4 s[4];
        __builtin_amdgcn_s_setprio(1);
#pragma unroll
        for (int cf = 0; cf < 4; ++cf) {
            f32x4 z = {};
            z = __builtin_amdgcn_mfma_f32_16x16x32_f16(ka[cf], qf0, z, 0, 0, 0);
            z = __builtin_amdgcn_mfma_f32_16x16x32_f16(kb[cf], qf1, z, 0, 0, 0);
            s[cf] = z;
        }
        __builtin_amdgcn_s_setprio(0);
        unsigned long long mw = mrow[t];
        unsigned w0 = (unsigned)mw, w1 = (unsigned)(mw >> 32);
#pragma unroll
        for (int cf = 0; cf < 4; ++cf) {
            unsigned wcb = (cf & 2) ? w1 : w0;
#pragma unroll
            for (int j = 0; j < 4; ++j) {
                unsigned sh = ((cf & 1) << 4) + g * 4 + j;
                s[cf][j] = ((wcb >> sh) & 1u) ? s[cf][j] * K2 : C2;
            }
        }
        float pmax = fmaxf(fmaxf(s[0][0], s[0][1]), fmaxf(s[0][2], s[0][3]));
#pragma unroll
        for (int cf = 1; cf < 4; ++cf)
            pmax = fmaxf(pmax, fmaxf(fmaxf(s[cf][0], s[cf][1]), fmaxf(s[cf][2], s[cf][3])));
        if (!__all(pmax <= m2 + 11.0f)) {      // defer-max (T13)
            pmax = fmaxf(pmax, __shfl_xor(pmax, 16));
            pmax = fmaxf(pmax, __shfl_xor(pmax, 32));
            float mnew = fmaxf(m2, pmax);
            float alpha = __builtin_amdgcn_exp2f(m2 - mnew);
#pragma unroll
            for (int df = 0; df < 4; ++df)
#pragma unroll
                for (int j = 0; j < 4; ++j) o[df][j] *= alpha;
            lsum *= alpha;
            m2 = mnew;
        }
        float rs = 0.f;
#pragma unroll
        for (int cf = 0; cf < 4; ++cf)
#pragma unroll
            for (int j = 0; j < 4; ++j) {
                float p = __builtin_amdgcn_exp2f(s[cf][j] - m2);
                s[cf][j] = p;
                rs += p;
            }
        lsum += rs;
#pragma unroll
        for (int cf = 0; cf < 4; ++cf) {
            h16x4 pk = {(h16)s[cf][0], (h16)s[cf][1], (h16)s[cf][2], (h16)s[cf][3]};
            int gran = (2 * cf + (g >> 1)) ^ (l & 7);
            *(h16x4*)(pbase + l * 128 + gran * 16 + (g & 1) * 8) = pk;
        }
#pragma unroll
        for (int ks = 0; ks < 2; ++ks) {
            int gr = (ks * 4 + g) ^ (l & 7);
            half8 pf = *(const half8*)(pbase + l * 128 + gr * 16);
            half8 vk[4];
#pragma unroll
            for (int df = 0; df < 4; ++df) {
                int row = df * 16 + l;
                vk[df] = *(const half8*)(Vl + row * 64 + (((ks * 4 + g) ^ (row & 7)) << 3));
            }
            __builtin_amdgcn_s_setprio(1);
#pragma unroll
            for (int df = 0; df < 4; ++df)
                o[df] = __builtin_amdgcn_mfma_f32_16x16x32_f16(vk[df], pf, o[df], 0, 0, 0);
            __builtin_amdgcn_s_setprio(0);
        }
        __syncthreads();                       // drains prefetch + protects buf reuse
    }

    lsum += __shfl_xor(lsum, 16);
    lsum += __shfl_xor(lsum, 32);
    float inv = 1.0f / lsum;
    int b = bh / HH, h = bh % HH;
    h16* xp = xh + (long)(b * SS + q0 + l) * EE + h * 64 + g * 4;
#pragma unroll
    for (int df = 0; df < 4; ++df) {
        h16x4 v4 = {(h16)(o[df][0] * inv), (h16)(o[df][1] * inv),
                    (h16)(o[df][2] * inv), (h16)(o[df][3] * inv)};
        *(h16x4*)(xp + df * 16) = v4;
    }
}

// ---------------- output GEMM: 64m x 64n tiles, 768 blocks, global_load_lds staging ----------------
__launch_bounds__(256)
__global__ void out_gemm_k(const h16* __restrict__ xh, const h16* __restrict__ Woh,
                           const float* __restrict__ bo, float* __restrict__ out) {
    __shared__ h16 As[64 * 64];
    __shared__ h16 Bs[64 * 64];
    const int bid = blockIdx.x;                    // 0..767
    const int idx = (bid & 7) * 96 + (bid >> 3);
    const int m0 = (idx / 12) * 64, n0 = (idx % 12) * 64;
    const int tid = threadIdx.x, lane = tid & 63, wid = tid >> 6;
    const int l = lane & 15, gq = lane >> 4;
    const int wr = wid >> 1, wc = wid & 1;
    f32x4 acc[2][2] = {};                          // wave: 32m x 32n

    for (int k0 = 0; k0 < EE; k0 += 64) {
#pragma unroll
        for (int it = 0; it < 2; ++it) {
            int e = it * 256 + tid;
            int row = e >> 3, slot = e & 7;
            int gsl = (slot ^ (row & 7)) << 3;
            gl_lds16(xh + (long)(m0 + row) * EE + k0 + gsl, As + e * 8);
            gl_lds16(Woh + (long)(n0 + row) * EE + k0 + gsl, Bs + e * 8);
        }
        __syncthreads();
#pragma unroll
        for (int ks = 0; ks < 2; ++ks) {
            half8 a[2], b[2];
#pragma unroll
            for (int rf = 0; rf < 2; ++rf) {
                int row = wr * 32 + rf * 16 + l;
                int g = (ks * 4 + gq) ^ (row & 7);
                a[rf] = *(const half8*)((const char*)As + row * 128 + (g << 4));
            }
#pragma unroll
            for (int cf = 0; cf < 2; ++cf) {
                int row = wc * 32 + cf * 16 + l;
                int g = (ks * 4 + gq) ^ (row & 7);
                b[cf] = *(const half8*)((const char*)Bs + row * 128 + (g << 4));
            }
            __builtin_amdgcn_s_setprio(1);
#pragma unroll
            for (int rf = 0; rf < 2; ++rf)
#pragma unroll
                for (int cf = 0; cf < 2; ++cf)
                    acc[rf][cf] = __builtin_amdgcn_mfma_f32_16x16x32_f16(a[rf], b[cf], acc[rf][cf], 0, 0, 0);
            __builtin_amdgcn_s_setprio(0);
        }
        __syncthreads();
    }
#pragma unroll
    for (int rf = 0; rf < 2; ++rf)
#pragma unroll
        for (int cf = 0; cf < 2; ++cf) {
            int n = n0 + wc * 32 + cf * 16 + l;
            float bias = bo[n];
#pragma unroll
            for (int j = 0; j < 4; ++j) {
                int m = m0 + wr * 32 + rf * 16 + gq * 4 + j;
                out[(long)m * EE + n] = acc[rf][cf][j] + bias;
            }
        }
}

extern "C" void kernel_launch(void* const* d_in, const int* in_sizes, int n_in,
                              void* d_out, int out_size, void* d_ws, size_t ws_size,
                              hipStream_t stream) {
    const float* key   = (const float*)d_in[0];
    const float* query = (const float*)d_in[1];
    const float* value = (const float*)d_in[2];
    const int*   mask  = (const int*)d_in[3];
    const float* Wk    = (const float*)d_in[4];
    const float* bk    = (const float*)d_in[5];
    const float* Wo    = (const float*)d_in[6];
    const float* bo    = (const float*)d_in[7];

    char* ws = (char*)d_ws;
    h16* keyh = (h16*)(ws + 0);                    // aliased by xh after proj
    h16* qryh = (h16*)(ws + 6291456);
    h16* valh = (h16*)(ws + 12582912);
    h16* qh   = (h16*)(ws + 18874368);
    h16* kh   = (h16*)(ws + 25165824);
    h16* vt   = (h16*)(ws + 31457280);
    h16* Wkh  = (h16*)(ws + 37748736);
    h16* Woh  = (h16*)(ws + 38928384);
    unsigned* mp = (unsigned*)(ws + 40108032);
    h16* xh = keyh;                                // reuse: keyh dead after proj
    float* out = (float*)d_out;

    hipLaunchKernelGGL(pack_mask_k, dim3(SS * SS / 32 / 256), dim3(256), 0, stream, mask, mp);
    hipLaunchKernelGGL(cvt_k, dim3(5184), dim3(256), 0, stream,
                       key, query, value, Wk, Wo, keyh, qryh, valh, Wkh, Woh);
    hipLaunchKernelGGL(proj_gemm_k, dim3(1152), dim3(256), 0, stream,
                       keyh, qryh, valh, Wkh, bk, kh, qh, vt);
    hipLaunchKernelGGL(attn_k, dim3(SS / 64 * BB * HH), dim3(256), 0, stream,
                       qh, kh, vt, (const unsigned long long*)mp, xh);
    hipLaunchKernelGGL(out_gemm_k, dim3(768), dim3(256), 0, stream, xh, Woh, bo, out);
}